// Round 1
// baseline (404.207 us; speedup 1.0000x reference)
//
#include <hip/hip_runtime.h>
#include <math.h>

#define Bq 64
#define Tq 2048
#define Eq 256
#define Dq 256
#define Iq 256

__device__ __forceinline__ float fast_tanh(float x) {
    // tanh(x) = 1 - 2/(exp(2x)+1); saturates correctly for |x| large.
    float e = __expf(2.0f * x);
    return 1.0f - 2.0f / (e + 1.0f);
}

// dec_proj[b][i] = sum_d dec[b][d] * w2[i][d]
__global__ __launch_bounds__(256) void dec_proj_kernel(
    const float* __restrict__ dec, const float* __restrict__ w2,
    float* __restrict__ dproj)
{
    const int b = blockIdx.x;
    const int i = threadIdx.x;   // 256 threads = 256 i
    __shared__ float dls[Dq];
    dls[i] = dec[b * Dq + i];
    __syncthreads();
    const float* w2r = w2 + i * Dq;
    float acc = 0.f;
    #pragma unroll 8
    for (int d = 0; d < Dq; ++d) acc += dls[d] * w2r[d];
    dproj[b * Iq + i] = acc;
}

// scores[b][t] = sum_i v[i] * tanh( sum_e enc[b][t][e]*w1[i][e] + dproj[b][i] )
// Block tile: 64 t x 256 i, K(=e) chunks of 32. 256 threads, 8x8 micro-tile.
__global__ __launch_bounds__(256) void scores_kernel(
    const float* __restrict__ enc,   // [B][T][E]
    const float* __restrict__ w1,    // [I][E]
    const float* __restrict__ v,     // [I]
    const float* __restrict__ dproj, // [B][I]
    float* __restrict__ scores)      // [B][T]
{
    const int b   = blockIdx.y;
    const int t0  = blockIdx.x * 64;
    const int tid = threadIdx.x;
    const int tx  = tid & 31;   // i dim (32 threads x 8 i)
    const int ty  = tid >> 5;   // t dim (8 threads x 8 t)

    __shared__ float As[32][68];    // [e][t], pad 68 (272B rows, 16B aligned)
    __shared__ float Bs[32][260];   // [e][i], pad 260 (1040B rows, 16B aligned)
    __shared__ float red[64][33];   // [t][tx] score partials

    float acc[8][8];
    #pragma unroll
    for (int a = 0; a < 8; ++a)
        #pragma unroll
        for (int c = 0; c < 8; ++c) acc[a][c] = 0.f;

    const float* encB = enc + ((size_t)b * Tq + t0) * Eq;

    for (int k0 = 0; k0 < Eq; k0 += 32) {
        // stage A: enc[t0+t][k0+e] -> As[e][t]; coalesced global reads
        {
            const int e  = tid & 31;
            const int tA = tid >> 5;       // 0..7
            #pragma unroll
            for (int r = 0; r < 8; ++r)
                As[e][tA + 8 * r] = encB[(tA + 8 * r) * Eq + k0 + e];
        }
        // stage B: w1[i][k0+e] -> Bs[e][i]; coalesced global reads
        {
            const int e = tid & 31;
            const int i = tid >> 5;        // 0..7
            #pragma unroll
            for (int r = 0; r < 32; ++r)
                Bs[e][i + 8 * r] = w1[(i + 8 * r) * Eq + k0 + e];
        }
        __syncthreads();
        #pragma unroll 8
        for (int k = 0; k < 32; ++k) {
            float4 a0 = *(const float4*)&As[k][4 * ty];
            float4 a1 = *(const float4*)&As[k][4 * ty + 32];
            float4 b0 = *(const float4*)&Bs[k][4 * tx];
            float4 b1 = *(const float4*)&Bs[k][4 * tx + 128];
            float am[8] = {a0.x, a0.y, a0.z, a0.w, a1.x, a1.y, a1.z, a1.w};
            float bn[8] = {b0.x, b0.y, b0.z, b0.w, b1.x, b1.y, b1.z, b1.w};
            #pragma unroll
            for (int mi = 0; mi < 8; ++mi)
                #pragma unroll
                for (int ni = 0; ni < 8; ++ni)
                    acc[mi][ni] += am[mi] * bn[ni];
        }
        __syncthreads();
    }

    // epilogue: tanh + v-dot, partial over this thread's 8 i's
    float sp[8] = {0.f, 0.f, 0.f, 0.f, 0.f, 0.f, 0.f, 0.f};
    #pragma unroll
    for (int ni = 0; ni < 8; ++ni) {
        const int i = (ni < 4) ? (4 * tx + ni) : (128 + 4 * tx + (ni - 4));
        const float dp = dproj[b * Iq + i];
        const float vi = v[i];
        #pragma unroll
        for (int mi = 0; mi < 8; ++mi)
            sp[mi] += vi * fast_tanh(acc[mi][ni] + dp);
    }
    // reduce over tx (32 threads) per t via LDS
    #pragma unroll
    for (int mi = 0; mi < 8; ++mi) {
        const int tl = (mi < 4) ? (4 * ty + mi) : (32 + 4 * ty + (mi - 4));
        red[tl][tx] = sp[mi];
    }
    __syncthreads();
    if (tid < 64) {
        float s = 0.f;
        #pragma unroll
        for (int j = 0; j < 32; ++j) s += red[tid][j];
        scores[(size_t)b * Tq + t0 + tid] = s;
    }
}

// in-place softmax over T per b
__global__ __launch_bounds__(256) void softmax_kernel(float* __restrict__ probs)
{
    const int b = blockIdx.x;
    float* row = probs + (size_t)b * Tq;
    const int tid = threadIdx.x;
    __shared__ float sred[256];

    float vals[8];
    float lmax = -INFINITY;
    #pragma unroll
    for (int j = 0; j < 8; ++j) {
        vals[j] = row[tid + 256 * j];
        lmax = fmaxf(lmax, vals[j]);
    }
    sred[tid] = lmax;
    __syncthreads();
    for (int s = 128; s > 0; s >>= 1) {
        if (tid < s) sred[tid] = fmaxf(sred[tid], sred[tid + s]);
        __syncthreads();
    }
    const float m = sred[0];
    __syncthreads();

    float lsum = 0.f;
    #pragma unroll
    for (int j = 0; j < 8; ++j) {
        vals[j] = __expf(vals[j] - m);
        lsum += vals[j];
    }
    sred[tid] = lsum;
    __syncthreads();
    for (int s = 128; s > 0; s >>= 1) {
        if (tid < s) sred[tid] += sred[tid + s];
        __syncthreads();
    }
    const float inv = 1.0f / sred[0];
    #pragma unroll
    for (int j = 0; j < 8; ++j) row[tid + 256 * j] = vals[j] * inv;
}

// ctx[b][e] += sum_{t in chunk} probs[b][t] * enc[b][t][e]
__global__ __launch_bounds__(256) void context_kernel(
    const float* __restrict__ enc, const float* __restrict__ probs,
    float* __restrict__ ctx)
{
    const int b  = blockIdx.y;
    const int t0 = blockIdx.x * 256;
    const int e  = threadIdx.x;
    __shared__ float p[256];
    p[threadIdx.x] = probs[(size_t)b * Tq + t0 + threadIdx.x];
    __syncthreads();
    const float* encP = enc + ((size_t)b * Tq + t0) * Eq + e;
    float a = 0.f;
    #pragma unroll 8
    for (int t = 0; t < 256; ++t) a += p[t] * encP[t * Eq];
    atomicAdd(&ctx[b * Eq + e], a);
}

extern "C" void kernel_launch(void* const* d_in, const int* in_sizes, int n_in,
                              void* d_out, int out_size, void* d_ws, size_t ws_size,
                              hipStream_t stream) {
    const float* enc = (const float*)d_in[0];  // [64][2048][256]
    const float* dec = (const float*)d_in[1];  // [64][256]
    const float* w1  = (const float*)d_in[2];  // [256][256]
    const float* w2  = (const float*)d_in[3];  // [256][256]
    const float* v   = (const float*)d_in[4];  // [1][256]

    float* out   = (float*)d_out;
    float* ctx   = out;                 // [64][256]   (output 0)
    float* probs = out + Bq * Eq;       // [64][2048]  (output 1, also scores scratch)
    float* dproj = (float*)d_ws;        // [64][256] scratch

    // context accumulated via atomics -> zero it (d_out is poisoned each call)
    hipMemsetAsync(ctx, 0, Bq * Eq * sizeof(float), stream);

    dec_proj_kernel<<<dim3(Bq), dim3(256), 0, stream>>>(dec, w2, dproj);
    scores_kernel<<<dim3(Tq / 64, Bq), dim3(256), 0, stream>>>(enc, w1, v, dproj, probs);
    softmax_kernel<<<dim3(Bq), dim3(256), 0, stream>>>(probs);
    context_kernel<<<dim3(Tq / 256, Bq), dim3(256), 0, stream>>>(enc, probs, ctx);
}

// Round 2
// 251.304 us; speedup vs baseline: 1.6084x; 1.6084x over previous
//
#include <hip/hip_runtime.h>
#include <hip/hip_bf16.h>
#include <math.h>

#define Bq 64
#define Tq 2048
#define Eq 256
#define Dq 256
#define Iq 256

using short8  = __attribute__((ext_vector_type(8))) short;
using floatx4 = __attribute__((ext_vector_type(4))) float;

__device__ __forceinline__ float fast_tanh(float x) {
    float e = __expf(2.0f * x);
    return 1.0f - 2.0f / (e + 1.0f);
}

__device__ __forceinline__ ushort f2bf(float x) {
    union { __hip_bfloat16 h; ushort u; } c;
    c.h = __float2bfloat16(x);
    return c.u;
}

// one-time w1 fp32 -> bf16 (same [I][E] row-major layout)
__global__ __launch_bounds__(256) void w1_cvt_kernel(
    const float* __restrict__ w1, ushort* __restrict__ w1b)
{
    const int idx = (blockIdx.x * 256 + threadIdx.x) * 4;
    float4 f = *(const float4*)&w1[idx];
    ushort4 u;
    u.x = f2bf(f.x); u.y = f2bf(f.y); u.z = f2bf(f.z); u.w = f2bf(f.w);
    *(ushort4*)&w1b[idx] = u;
}

// dec_proj[b][i] = sum_d dec[b][d] * w2[i][d]
__global__ __launch_bounds__(256) void dec_proj_kernel(
    const float* __restrict__ dec, const float* __restrict__ w2,
    float* __restrict__ dproj)
{
    const int b = blockIdx.x;
    const int i = threadIdx.x;
    __shared__ float dls[Dq];
    dls[i] = dec[b * Dq + i];
    __syncthreads();
    const float* w2r = w2 + i * Dq;
    float acc = 0.f;
    #pragma unroll 8
    for (int d = 0; d < Dq; ++d) acc += dls[d] * w2r[d];
    dproj[b * Iq + i] = acc;
}

// scores[b][t] = sum_i v[i]*tanh( (enc @ w1^T)[t][i] + dproj[b][i] )
// MFMA 16x16x32 bf16. Block: 64 t x 256 i, 4 waves; wave w handles
// i in [w*64, w*64+64) with a 4(m) x 4(n) tile grid. K chunks of 64.
__global__ __launch_bounds__(256) void scores_mfma_kernel(
    const float*  __restrict__ enc,   // [B][T][E] fp32
    const ushort* __restrict__ w1b,   // [I][E] bf16 bits
    const float*  __restrict__ v,     // [I]
    const float*  __restrict__ dproj, // [B][I]
    float* __restrict__ scores)       // [B][T]
{
    const int b   = blockIdx.y;
    const int t0  = blockIdx.x * 64;
    const int tid = threadIdx.x;
    const int w   = tid >> 6;       // wave 0..3
    const int l   = tid & 63;
    const int l15 = l & 15;
    const int lq  = l >> 4;         // quarter 0..3

    // pad to 72 bf16 (144 B = 36 banks): balanced b128 frag reads
    __shared__ ushort As[64 * 72];      //  9.2 KB  [t][e] bf16
    __shared__ ushort Bs[256 * 72];     // 36.9 KB  [i][e] bf16
    __shared__ float  vls[Iq], dls[Iq];
    __shared__ float  red[64][5];

    vls[tid] = v[tid];
    dls[tid] = dproj[b * Iq + tid];

    floatx4 acc[4][4];
    #pragma unroll
    for (int mi = 0; mi < 4; ++mi)
        #pragma unroll
        for (int ni = 0; ni < 4; ++ni)
            acc[mi][ni] = (floatx4)0.f;

    const float* encB = enc + ((size_t)b * Tq + t0) * Eq;

    for (int k0 = 0; k0 < Eq; k0 += 64) {
        // stage A: enc[t0+row][k0..k0+63] -> As, fp32->bf16. 1024 float4 loads.
        #pragma unroll
        for (int r = 0; r < 4; ++r) {
            const int idx = tid + 256 * r;
            const int row = idx >> 4;
            const int c4  = (idx & 15) * 4;
            float4 f = *(const float4*)&encB[row * Eq + k0 + c4];
            ushort4 u;
            u.x = f2bf(f.x); u.y = f2bf(f.y); u.z = f2bf(f.z); u.w = f2bf(f.w);
            *(ushort4*)&As[row * 72 + c4] = u;
        }
        // stage B: w1b[row][k0..k0+63] -> Bs. 2048 x 16B loads.
        #pragma unroll
        for (int r = 0; r < 8; ++r) {
            const int idx = tid + 256 * r;
            const int row = idx >> 3;
            const int c8  = (idx & 7) * 8;
            short8 u = *(const short8*)&w1b[row * Eq + k0 + c8];
            *(short8*)&Bs[row * 72 + c8] = u;
        }
        __syncthreads();
        #pragma unroll
        for (int ks = 0; ks < 2; ++ks) {
            const int kloc = ks * 32 + lq * 8;
            short8 af[4], bf[4];
            #pragma unroll
            for (int mi = 0; mi < 4; ++mi)
                af[mi] = *(const short8*)&As[(mi * 16 + l15) * 72 + kloc];
            #pragma unroll
            for (int ni = 0; ni < 4; ++ni)
                bf[ni] = *(const short8*)&Bs[(w * 64 + ni * 16 + l15) * 72 + kloc];
            #pragma unroll
            for (int mi = 0; mi < 4; ++mi)
                #pragma unroll
                for (int ni = 0; ni < 4; ++ni)
                    acc[mi][ni] = __builtin_amdgcn_mfma_f32_16x16x32_bf16(
                        af[mi], bf[ni], acc[mi][ni], 0, 0, 0);
        }
        __syncthreads();
    }

    // epilogue: tanh + v-weight, then reduce over i.
    // C layout: col(=i local) = l15, row(=t local) = lq*4 + reg.
    float part[4][4];   // [mi][reg]
    #pragma unroll
    for (int mi = 0; mi < 4; ++mi)
        #pragma unroll
        for (int r = 0; r < 4; ++r) part[mi][r] = 0.f;

    #pragma unroll
    for (int ni = 0; ni < 4; ++ni) {
        const int i  = w * 64 + ni * 16 + l15;
        const float vi = vls[i];
        const float dp = dls[i];
        #pragma unroll
        for (int mi = 0; mi < 4; ++mi)
            #pragma unroll
            for (int r = 0; r < 4; ++r)
                part[mi][r] += vi * fast_tanh(acc[mi][ni][r] + dp);
    }
    // sum across the 16 lanes of each quarter (they hold different i, same t)
    #pragma unroll
    for (int mi = 0; mi < 4; ++mi)
        #pragma unroll
        for (int r = 0; r < 4; ++r) {
            float s = part[mi][r];
            s += __shfl_xor(s, 1);
            s += __shfl_xor(s, 2);
            s += __shfl_xor(s, 4);
            s += __shfl_xor(s, 8);
            if (l15 == 0) red[mi * 16 + lq * 4 + r][w] = s;
        }
    __syncthreads();
    if (tid < 64) {
        const float s = red[tid][0] + red[tid][1] + red[tid][2] + red[tid][3];
        scores[(size_t)b * Tq + t0 + tid] = s;
    }
}

// in-place softmax over T per b
__global__ __launch_bounds__(256) void softmax_kernel(float* __restrict__ probs)
{
    const int b = blockIdx.x;
    float* row = probs + (size_t)b * Tq;
    const int tid = threadIdx.x;
    __shared__ float sred[256];

    float vals[8];
    float lmax = -INFINITY;
    #pragma unroll
    for (int j = 0; j < 8; ++j) {
        vals[j] = row[tid + 256 * j];
        lmax = fmaxf(lmax, vals[j]);
    }
    sred[tid] = lmax;
    __syncthreads();
    for (int s = 128; s > 0; s >>= 1) {
        if (tid < s) sred[tid] = fmaxf(sred[tid], sred[tid + s]);
        __syncthreads();
    }
    const float m = sred[0];
    __syncthreads();

    float lsum = 0.f;
    #pragma unroll
    for (int j = 0; j < 8; ++j) {
        vals[j] = __expf(vals[j] - m);
        lsum += vals[j];
    }
    sred[tid] = lsum;
    __syncthreads();
    for (int s = 128; s > 0; s >>= 1) {
        if (tid < s) sred[tid] += sred[tid + s];
        __syncthreads();
    }
    const float inv = 1.0f / sred[0];
    #pragma unroll
    for (int j = 0; j < 8; ++j) row[tid + 256 * j] = vals[j] * inv;
}

// ctx[b][e] += sum_{t in chunk} probs[b][t] * enc[b][t][e]
__global__ __launch_bounds__(256) void context_kernel(
    const float* __restrict__ enc, const float* __restrict__ probs,
    float* __restrict__ ctx)
{
    const int b  = blockIdx.y;
    const int t0 = blockIdx.x * 256;
    const int e  = threadIdx.x;
    __shared__ float p[256];
    p[threadIdx.x] = probs[(size_t)b * Tq + t0 + threadIdx.x];
    __syncthreads();
    const float* encP = enc + ((size_t)b * Tq + t0) * Eq + e;
    float a = 0.f;
    #pragma unroll 8
    for (int t = 0; t < 256; ++t) a += p[t] * encP[t * Eq];
    atomicAdd(&ctx[b * Eq + e], a);
}

extern "C" void kernel_launch(void* const* d_in, const int* in_sizes, int n_in,
                              void* d_out, int out_size, void* d_ws, size_t ws_size,
                              hipStream_t stream) {
    const float* enc = (const float*)d_in[0];  // [64][2048][256]
    const float* dec = (const float*)d_in[1];  // [64][256]
    const float* w1  = (const float*)d_in[2];  // [256][256]
    const float* w2  = (const float*)d_in[3];  // [256][256]
    const float* v   = (const float*)d_in[4];  // [1][256]

    float* out   = (float*)d_out;
    float* ctx   = out;                 // [64][256]   (output 0)
    float* probs = out + Bq * Eq;       // [64][2048]  (output 1, scores scratch)

    float*  dproj = (float*)d_ws;                    // 64 KB
    ushort* w1b   = (ushort*)((char*)d_ws + Bq * Iq * sizeof(float)); // 128 KB

    hipMemsetAsync(ctx, 0, Bq * Eq * sizeof(float), stream);

    w1_cvt_kernel<<<dim3((Iq * Eq) / 1024), dim3(256), 0, stream>>>(w1, w1b);
    dec_proj_kernel<<<dim3(Bq), dim3(256), 0, stream>>>(dec, w2, dproj);
    scores_mfma_kernel<<<dim3(Tq / 64, Bq), dim3(256), 0, stream>>>(enc, w1b, v, dproj, probs);
    softmax_kernel<<<dim3(Bq), dim3(256), 0, stream>>>(probs);
    context_kernel<<<dim3(Tq / 256, Bq), dim3(256), 0, stream>>>(enc, probs, ctx);
}